// Round 1
// baseline (229.169 us; speedup 1.0000x reference)
//
#include <hip/hip_runtime.h>
#include <stdint.h>

typedef short short8 __attribute__((ext_vector_type(8)));
typedef float float4v __attribute__((ext_vector_type(4)));
typedef unsigned long long ull;

// Problem sizes (fixed): N=8, M=512, D=64, B=8192, H=W=1
// Block: one n, 128 rows of b, 512 threads (8 waves), wave owns 16 rows x all 512 m.

#define LDS_E    0        // embedding bf16 [512 m][128 B rows], XOR-swizzled
#define LDS_X    65536    // x tile bf16 [128 r][128 B rows], XOR-swizzled
#define LDS_ESQ  81920    // e_sq fp32 [512]
#define LDS_SAMP 83968    // per-wave samp chunk: 8 waves x 4096 B ([128 m][16 r] bf16)
#define LDS_AVG  116736   // per-wave avg_probs partials fp32 [8][512]
#define LDS_KL   133120   // per-wave KL partials fp32 [8]
#define LDS_SZ   133184

__device__ __forceinline__ unsigned short f2bf(float f){
  unsigned u = __float_as_uint(f);
  return (unsigned short)((u + 0x7FFFu + ((u >> 16) & 1u)) >> 16);
}

template<int OFF>
__device__ __forceinline__ ull tr16(unsigned a){
  ull d;
  asm volatile("ds_read_b64_tr_b16 %0, %1 offset:%c2" : "=v"(d) : "v"(a), "i"(OFF));
  return d;
}

__device__ __forceinline__ short8 mk8(ull lo, ull hi){
  union { ull q[2]; short8 v; } u; u.q[0] = lo; u.q[1] = hi; return u.v;
}

// One K-tile (32 m) of the quantize GEMM. A = samples (tr-read from wave-private
// chunk), B = embedding (tr-read from swizzled e_raw). Both sides use the SAME
// k-permutation pi (element j, lane-group kg -> m = 4*kg + j (+16 for j>=4)),
// which is MFMA-invariant when applied to A and B consistently.
#define DO_KT(KT) do { \
    ull alo = tr16<(KT)*1024      >(trA); \
    ull ahi = tr16<(KT)*1024 + 512>(trA); \
    ull b0l = tr16<(KT)*4096       >(trBc0); \
    ull b0h = tr16<(KT)*4096 + 2048>(trBc0); \
    ull b1l = tr16<(KT)*4096       >(trBc1); \
    ull b1h = tr16<(KT)*4096 + 2048>(trBc1); \
    ull b2l = tr16<(KT)*4096       >(trBc2); \
    ull b2h = tr16<(KT)*4096 + 2048>(trBc2); \
    ull b3l = tr16<(KT)*4096       >(trBc3); \
    ull b3h = tr16<(KT)*4096 + 2048>(trBc3); \
    asm volatile("s_waitcnt lgkmcnt(0)" ::: "memory"); \
    __builtin_amdgcn_sched_barrier(0); \
    short8 aa = mk8(alo, ahi); \
    qacc0 = __builtin_amdgcn_mfma_f32_16x16x32_bf16(aa, mk8(b0l, b0h), qacc0, 0, 0, 0); \
    qacc1 = __builtin_amdgcn_mfma_f32_16x16x32_bf16(aa, mk8(b1l, b1h), qacc1, 0, 0, 0); \
    qacc2 = __builtin_amdgcn_mfma_f32_16x16x32_bf16(aa, mk8(b2l, b2h), qacc2, 0, 0, 0); \
    qacc3 = __builtin_amdgcn_mfma_f32_16x16x32_bf16(aa, mk8(b3l, b3h), qacc3, 0, 0, 0); \
  } while (0)

extern "C" __global__ void __launch_bounds__(512, 2)
vq_main(const float* __restrict__ gx, const float* __restrict__ ge,
        const float* __restrict__ gu, const float* __restrict__ gtau,
        float* __restrict__ gq, float* __restrict__ glg,
        float* __restrict__ ws_avg, float* __restrict__ ws_kl)
{
  extern __shared__ char smem[];
  const int tid = threadIdx.x;
  const int n   = blockIdx.x >> 6;
  const int b0  = (blockIdx.x & 63) * 128;

  // ---- stage embedding -> bf16 LDS rows (swizzled) + e_sq (fp32) ----
  {
    const int m = tid;                       // 512 threads, one m-row each
    const float* src = ge + (size_t)(n * 512 + m) * 64;
    char* dst = smem + LDS_E + m * 128;
    const unsigned sw = (unsigned)((m & 7) << 4);
    float esq = 0.f;
#pragma unroll
    for (int c = 0; c < 8; ++c) {
      float4 a = *(const float4*)(src + c * 8);
      float4 b = *(const float4*)(src + c * 8 + 4);
      esq += a.x*a.x + a.y*a.y + a.z*a.z + a.w*a.w
           + b.x*b.x + b.y*b.y + b.z*b.z + b.w*b.w;
      short8 v = { (short)f2bf(a.x), (short)f2bf(a.y), (short)f2bf(a.z), (short)f2bf(a.w),
                   (short)f2bf(b.x), (short)f2bf(b.y), (short)f2bf(b.z), (short)f2bf(b.w) };
      *(short8*)(dst + (((unsigned)(c * 16)) ^ sw)) = v;
    }
    ((float*)(smem + LDS_ESQ))[m] = esq;
  }
  // ---- stage x tile -> bf16 LDS rows (swizzled) ----
  {
    const int r = tid >> 2, qq = tid & 3;    // 4 threads per row
    const float* src = gx + (size_t)(b0 + r) * 512 + n * 64 + qq * 16;
    char* dst = smem + LDS_X + r * 128;
    const unsigned sw = (unsigned)((r & 7) << 4);
#pragma unroll
    for (int h = 0; h < 2; ++h) {
      float4 a = *(const float4*)(src + h * 8);
      float4 b = *(const float4*)(src + h * 8 + 4);
      short8 v = { (short)f2bf(a.x), (short)f2bf(a.y), (short)f2bf(a.z), (short)f2bf(a.w),
                   (short)f2bf(b.x), (short)f2bf(b.y), (short)f2bf(b.z), (short)f2bf(b.w) };
      *(short8*)(dst + (((unsigned)((qq * 2 + h) * 16)) ^ sw)) = v;
    }
  }
  __syncthreads();

  const int lane = tid & 63;
  const int w    = tid >> 6;
  const int l15  = lane & 15;
  const int kg   = lane >> 4;
  const unsigned swl = (unsigned)((l15 & 7) << 4);

  // ---- phase A: acc = X_bf16 . E_bf16^T  (K=64, two 16x16x32 MFMAs per m-tile) ----
  const char* xrow = smem + LDS_X + (w * 16 + l15) * 128;
  const short8 a0 = *(const short8*)(xrow + (((unsigned)(kg * 16)) ^ swl));
  const short8 a1 = *(const short8*)(xrow + (((unsigned)(64 + kg * 16)) ^ swl));

  const char* erow = smem + LDS_E + l15 * 128;
  const unsigned eo0 = ((unsigned)(kg * 16)) ^ swl;
  const unsigned eo1 = ((unsigned)(64 + kg * 16)) ^ swl;

  float4v acc[32];
#pragma unroll
  for (int t = 0; t < 32; ++t) acc[t] = (float4v){0.f, 0.f, 0.f, 0.f};
#pragma unroll
  for (int t = 0; t < 32; ++t) {
    short8 bb0 = *(const short8*)(erow + t * 2048 + eo0);
    short8 bb1 = *(const short8*)(erow + t * 2048 + eo1);
    acc[t] = __builtin_amdgcn_mfma_f32_16x16x32_bf16(a0, bb0, acc[t], 0, 0, 0);
    acc[t] = __builtin_amdgcn_mfma_f32_16x16x32_bf16(a1, bb1, acc[t], 0, 0, 0);
  }

  // ---- s = 2*dot - e_sq ; row max (16-lane group reduce; row = kg*4+j) ----
  const float* esqp = (const float*)(smem + LDS_ESQ);
  float rmax[4] = {-3e38f, -3e38f, -3e38f, -3e38f};
#pragma unroll
  for (int t = 0; t < 32; ++t) {
    const float eq = esqp[t * 16 + l15];
#pragma unroll
    for (int j = 0; j < 4; ++j) {
      const float v = 2.f * acc[t][j] - eq;
      acc[t][j] = v;
      rmax[j] = fmaxf(rmax[j], v);
    }
  }
#pragma unroll
  for (int j = 0; j < 4; ++j)
#pragma unroll
    for (int o = 1; o < 16; o <<= 1) rmax[j] = fmaxf(rmax[j], __shfl_xor(rmax[j], o));

  float Z[4] = {0.f, 0.f, 0.f, 0.f};
#pragma unroll
  for (int t = 0; t < 32; ++t)
#pragma unroll
    for (int j = 0; j < 4; ++j) Z[j] += __expf(acc[t][j] - rmax[j]);
#pragma unroll
  for (int j = 0; j < 4; ++j)
#pragma unroll
    for (int o = 1; o < 16; o <<= 1) Z[j] += __shfl_xor(Z[j], o);
  float lse[4];
#pragma unroll
  for (int j = 0; j < 4; ++j) lse[j] = rmax[j] + __logf(Z[j]);

  // ---- pass 2: write log_probs, gumbel, KL partial, y = (lp+g)/tau ----
  const float invtau = 1.0f / gtau[0];
  const float logM = 6.2383246250395075f;   // log(512)
  float* lpp[4]; const float* upp[4];
#pragma unroll
  for (int j = 0; j < 4; ++j) {
    const int bj = b0 + w * 16 + kg * 4 + j;
    lpp[j] = glg + (size_t)bj * 4096 + n * 512 + l15;
    upp[j] = gu + (size_t)n * 4194304 + (size_t)bj * 512 + l15;
  }
  float m2[4] = {-3e38f, -3e38f, -3e38f, -3e38f};
  float kl[4] = {0.f, 0.f, 0.f, 0.f};
#pragma unroll
  for (int t = 0; t < 32; ++t) {
#pragma unroll
    for (int j = 0; j < 4; ++j) {
      const float lp = acc[t][j] - lse[j];
      lpp[j][t * 16] = lp;
      const float uu = upp[j][t * 16];
      const float g = -__logf(-__logf(uu));
      const float p = __expf(lp);
      kl[j] += p * (lp + logM);
      const float y = (lp + g) * invtau;
      m2[j] = fmaxf(m2[j], y);
      acc[t][j] = y;
    }
  }
#pragma unroll
  for (int j = 0; j < 4; ++j)
#pragma unroll
    for (int o = 1; o < 16; o <<= 1) m2[j] = fmaxf(m2[j], __shfl_xor(m2[j], o));

  // ---- pass 3: second softmax numerators + denom ----
  float Z2[4] = {0.f, 0.f, 0.f, 0.f};
#pragma unroll
  for (int t = 0; t < 32; ++t)
#pragma unroll
    for (int j = 0; j < 4; ++j) {
      const float e3 = __expf(acc[t][j] - m2[j]);
      acc[t][j] = e3;
      Z2[j] += e3;
    }
#pragma unroll
  for (int j = 0; j < 4; ++j)
#pragma unroll
    for (int o = 1; o < 16; o <<= 1) Z2[j] += __shfl_xor(Z2[j], o);
  float r2[4];
#pragma unroll
  for (int j = 0; j < 4; ++j) r2[j] = 1.0f / Z2[j];

  // ---- pass 4 + phase B: samples -> LDS chunk (bf16) -> quantize GEMM ----
  char* sampb = smem + LDS_SAMP + w * 4096;
  const unsigned trA = (unsigned)(uintptr_t)sampb
                     + (unsigned)(kg * 128 + (l15 >> 2) * 32 + (l15 & 3) * 8);
  const int mrow = kg * 4 + (l15 >> 2);
  const unsigned ebase = (unsigned)(uintptr_t)(smem + LDS_E) + (unsigned)(mrow * 128);
  const unsigned msw = ((unsigned)(mrow & 7)) << 4;
  unsigned trBc0 = ebase + ((unsigned)(  0 + (l15 & 3) * 8) ^ msw);
  unsigned trBc1 = ebase + ((unsigned)( 32 + (l15 & 3) * 8) ^ msw);
  unsigned trBc2 = ebase + ((unsigned)( 64 + (l15 & 3) * 8) ^ msw);
  unsigned trBc3 = ebase + ((unsigned)( 96 + (l15 & 3) * 8) ^ msw);

  float4v qacc0 = (float4v){0.f,0.f,0.f,0.f};
  float4v qacc1 = (float4v){0.f,0.f,0.f,0.f};
  float4v qacc2 = (float4v){0.f,0.f,0.f,0.f};
  float4v qacc3 = (float4v){0.f,0.f,0.f,0.f};

#pragma unroll
  for (int c = 0; c < 4; ++c) {
#pragma unroll
    for (int tt = 0; tt < 8; ++tt) {
      const int t = c * 8 + tt;
      const float s0 = acc[t][0] * r2[0];
      const float s1 = acc[t][1] * r2[1];
      const float s2 = acc[t][2] * r2[2];
      const float s3 = acc[t][3] * r2[3];
      const ull pk = (ull)f2bf(s0) | ((ull)f2bf(s1) << 16)
                   | ((ull)f2bf(s2) << 32) | ((ull)f2bf(s3) << 48);
      *(ull*)(sampb + (tt * 16 + l15) * 32 + kg * 8) = pk;
      acc[t][0] = s0 + s1 + s2 + s3;     // avg_probs partial (this m, 4 rows)
    }
    asm volatile("s_waitcnt lgkmcnt(0)" ::: "memory");
    __builtin_amdgcn_sched_barrier(0);
    DO_KT(0); DO_KT(1); DO_KT(2); DO_KT(3);
    trBc0 += 16384; trBc1 += 16384; trBc2 += 16384; trBc3 += 16384;
  }

  // ---- store quantized: q[b][n*64+d] ----
  {
    const size_t qb = (size_t)(b0 + w * 16 + kg * 4) * 512 + n * 64 + l15;
#pragma unroll
    for (int j = 0; j < 4; ++j) {
      gq[qb + (size_t)j * 512 +  0] = qacc0[j];
      gq[qb + (size_t)j * 512 + 16] = qacc1[j];
      gq[qb + (size_t)j * 512 + 32] = qacc2[j];
      gq[qb + (size_t)j * 512 + 48] = qacc3[j];
    }
  }

  // ---- avg_probs + KL wave partials -> LDS, then block partials -> ws ----
  float* avgl = (float*)(smem + LDS_AVG);
#pragma unroll
  for (int t = 0; t < 32; ++t) {
    float av = acc[t][0];
    av += __shfl_xor(av, 16);
    av += __shfl_xor(av, 32);
    if (kg == 0) avgl[w * 512 + t * 16 + l15] = av;
  }
  float klv = kl[0] + kl[1] + kl[2] + kl[3];
#pragma unroll
  for (int o = 1; o < 64; o <<= 1) klv += __shfl_xor(klv, o);
  if (lane == 0) ((float*)(smem + LDS_KL))[w] = klv;
  __syncthreads();
  {
    float s = 0.f;
#pragma unroll
    for (int ww = 0; ww < 8; ++ww) s += avgl[ww * 512 + tid];
    ws_avg[(size_t)blockIdx.x * 512 + tid] = s;
    if (tid == 0) {
      float k = 0.f;
      const float* klp = (const float*)(smem + LDS_KL);
#pragma unroll
      for (int i = 0; i < 8; ++i) k += klp[i];
      ws_kl[blockIdx.x] = k;
    }
  }
}

extern "C" __global__ void __launch_bounds__(512)
vq_fin(const float* __restrict__ ws_avg, const float* __restrict__ ws_kl,
       float* __restrict__ scal)
{
  __shared__ float red[8];
  const int tid = threadIdx.x, lane = tid & 63, w = tid >> 6;
  float pps = 0.f;
  for (int n = 0; n < 8; ++n) {
    float s = 0.f;
    for (int bt = 0; bt < 64; ++bt) s += ws_avg[(size_t)(n * 64 + bt) * 512 + tid];
    const float avg = s * (1.0f / 8192.0f);
    float term = avg * __logf(avg + 1e-10f);
#pragma unroll
    for (int o = 1; o < 64; o <<= 1) term += __shfl_xor(term, o);
    __syncthreads();
    if (lane == 0) red[w] = term;
    __syncthreads();
    if (tid == 0) {
      float tt = 0.f;
#pragma unroll
      for (int i = 0; i < 8; ++i) tt += red[i];
      pps += __expf(-tt);
    }
  }
  float kv = ws_kl[tid];
#pragma unroll
  for (int o = 1; o < 64; o <<= 1) kv += __shfl_xor(kv, o);
  __syncthreads();
  if (lane == 0) red[w] = kv;
  __syncthreads();
  if (tid == 0) {
    float k = 0.f;
#pragma unroll
    for (int i = 0; i < 8; ++i) k += red[i];
    scal[0] = k * (1.0f / 8192.0f);   // KL.sum over (n,m) / B
    scal[1] = pps;                    // perplexity.sum()
  }
}

extern "C" void kernel_launch(void* const* d_in, const int* in_sizes, int n_in,
                              void* d_out, int out_size, void* d_ws, size_t ws_size,
                              hipStream_t stream)
{
  const float* gx = (const float*)d_in[0];
  const float* ge = (const float*)d_in[1];
  const float* gu = (const float*)d_in[2];
  const float* gt = (const float*)d_in[3];
  float* out  = (float*)d_out;
  float* gq   = out;                  // (B, N, D, 1, 1) = 4194304 floats
  float* scal = out + 4194304;        // [KL, perplexity_sum]
  float* glg  = out + 4194306;        // (B, N, M, 1, 1) = 33554432 floats
  float* ws_avg = (float*)d_ws;       // [512 blocks][512 m]
  float* ws_kl  = ws_avg + 512 * 512; // [512 blocks]

  hipFuncSetAttribute((const void*)vq_main,
                      hipFuncAttributeMaxDynamicSharedMemorySize, LDS_SZ);
  vq_main<<<dim3(512), dim3(512), LDS_SZ, stream>>>(gx, ge, gu, gt, gq, glg, ws_avg, ws_kl);
  vq_fin<<<dim3(1), dim3(512), 0, stream>>>(ws_avg, ws_kl, scal);
}